// Round 7
// baseline (944.268 us; speedup 1.0000x reference)
//
#include <hip/hip_runtime.h>
#include <hip/hip_bf16.h>

#define DIN 128
#define HID 32
#define EPS 1e-5f
#define FXS 16777216.0f             // 2^24 fixed-point scale for deg accumulation
#define FXI 5.9604644775390625e-8f  // 2^-24
#define NSPLIT 4                    // src-quartile sub-bins (gather L2 residency)

typedef unsigned int u32;
typedef unsigned short u16;
typedef unsigned long long u64;

// extract bf16 half (hi=0 -> low 16 bits = even channel) as float
__device__ __forceinline__ float bfx(u32 v, int hi) {
    return __uint_as_float(hi ? (v & 0xffff0000u) : (v << 16));
}

__device__ __forceinline__ u16 f2bf(float f) {
    __hip_bfloat16 h = __float2bfloat16(f);
    return *reinterpret_cast<u16*>(&h);
}

// ---------------- init: zero u64 count/deg accumulator + BN stats ----------------
__global__ void init_cnt(u64* __restrict__ cnt64, float* __restrict__ stats, int n4) {
    int i = blockIdx.x * blockDim.x + threadIdx.x;
    if (i < n4) cnt64[i] = 0ull;
    if (i < 192) stats[i] = 0.f;
}

// one u64 atomic per edge into bin (q*N + col): count(hi32) + fixpoint w(lo32)
__global__ void hist_rank(const int* __restrict__ row, const int* __restrict__ col,
                          const float* __restrict__ w, u64* __restrict__ cnt64,
                          int* __restrict__ rank, int E, int n, u32 qdiv) {
    int e = blockIdx.x * blockDim.x + threadIdx.x;
    if (e < E) {
        int c = col[e];
        u32 q = (u32)row[e] / qdiv;
        u32 fx = (u32)(w[e] * FXS + 0.5f);
        u64 old = atomicAdd(&cnt64[(size_t)q * n + c], (1ull << 32) | (u64)fx);
        rank[e] = (int)(old >> 32);
    }
}

// per-node: 4 sub-bin counts -> rowptr (pre-scan), total deg -> dinv
__global__ void finalize_deg(const u64* __restrict__ cnt64, int* __restrict__ rowptr,
                             float* __restrict__ dinv, int n) {
    int i = blockIdx.x * blockDim.x + threadIdx.x;
    if (i < n) {
        float degw = 0.f;
#pragma unroll
        for (int q = 0; q < NSPLIT; ++q) {
            u64 v = cnt64[(size_t)q * n + i];
            rowptr[q * n + i] = (int)(v >> 32);
            degw += (float)(u32)v;
        }
        dinv[i] = rsqrtf(1.0f + degw * FXI);  // +1 self loop
    }
}

// ---------------- exclusive scan (multi-level) ----------------
__global__ void scan_blocks(int* __restrict__ data, int* __restrict__ bsum, int n) {
    __shared__ int s[256];
    int i = blockIdx.x * 256 + threadIdx.x;
    int v = (i < n) ? data[i] : 0;
    s[threadIdx.x] = v;
    __syncthreads();
    for (int off = 1; off < 256; off <<= 1) {
        int t = (threadIdx.x >= off) ? s[threadIdx.x - off] : 0;
        __syncthreads();
        s[threadIdx.x] += t;
        __syncthreads();
    }
    if (i < n) data[i] = s[threadIdx.x] - v;  // exclusive
    if (threadIdx.x == 255) bsum[blockIdx.x] = s[255];
}

__global__ void scan_tops(int* __restrict__ bsum, int nb) {
    __shared__ int s[512];
    int v = (threadIdx.x < nb) ? bsum[threadIdx.x] : 0;
    s[threadIdx.x] = v;
    __syncthreads();
    for (int off = 1; off < 512; off <<= 1) {
        int t = (threadIdx.x >= off) ? s[threadIdx.x - off] : 0;
        __syncthreads();
        s[threadIdx.x] += t;
        __syncthreads();
    }
    if (threadIdx.x < nb) bsum[threadIdx.x] = s[threadIdx.x] - v;  // exclusive
}

// data[i] += bsum[block]; also writes sentinel data[n] = E (harmless slack on inner levels)
__global__ void scan_addback(int* __restrict__ data, const int* __restrict__ bsum,
                             int n, int E) {
    int i = blockIdx.x * 256 + threadIdx.x;
    if (i < n) data[i] += bsum[blockIdx.x];
    if (i == n) data[n] = E;  // sentinel end
}

// ---------------- atomic-free scatter into split CSR ----------------
__global__ void scatter_pos(const int* __restrict__ row, const int* __restrict__ col,
                            const float* __restrict__ w, const float* __restrict__ dinv,
                            const int* __restrict__ rowptr, const int* __restrict__ rank,
                            int2* __restrict__ esort, int E, int n, u32 qdiv) {
    int e = blockIdx.x * blockDim.x + threadIdx.x;
    if (e < E) {
        int r = row[e], c = col[e];
        u32 q = (u32)r / qdiv;
        float nv = dinv[r] * w[e] * dinv[c];
        int pos = rowptr[(size_t)q * n + c] + rank[e];
        esort[pos] = make_int2(r, __float_as_int(nv));
    }
}

// ---------------- layer-0 GEMM (x fp32 -> h bf16) ----------------
__global__ void gemm_din(const float* __restrict__ x, const float* __restrict__ W,
                         u16* __restrict__ hb, int n) {
    __shared__ float Wl[DIN * HID];
    for (int i = threadIdx.x; i < DIN * HID; i += blockDim.x) Wl[i] = W[i];
    __syncthreads();
    int ch = threadIdx.x & 31;
    int node = blockIdx.x * 8 + (threadIdx.x >> 5);
    if (node >= n) return;
    const float* xr = x + (size_t)node * DIN;
    float acc = 0.f;
#pragma unroll 8
    for (int k = 0; k < DIN; ++k) acc += xr[k] * Wl[k * HID + ch];
    hb[node * HID + ch] = f2bf(acc);
}

// ---------------- hidden GEMM with fused BN+ReLU on the input ----------------
// reads raw agg, applies per-channel affine (from stats) + relu, then @W -> bf16
__global__ void gemm_hid_bn(const float* __restrict__ a, const float* __restrict__ W,
                            const float* __restrict__ stats, const float* __restrict__ g,
                            const float* __restrict__ be, u16* __restrict__ hb,
                            int n, float invN) {
    __shared__ float Wl[HID * HID];
    __shared__ float sc[HID], sh[HID];
    int t = threadIdx.x;
    for (int i = t; i < HID * HID; i += blockDim.x) Wl[i] = W[i];
    if (t < HID) {
        float mu = stats[t] * invN;
        float var = stats[32 + t] * invN - mu * mu;
        float s = rsqrtf(var + EPS) * g[t];
        sc[t] = s;
        sh[t] = be[t] - mu * s;
    }
    __syncthreads();
    int ch = t & 31;
    int node = blockIdx.x * 8 + (t >> 5);
    if (node >= n) return;
    const float* ar = a + (size_t)node * HID;
    float acc = 0.f;
#pragma unroll
    for (int k = 0; k < HID; ++k) {
        float v = fmaxf(ar[k] * sc[k] + sh[k], 0.f);
        acc += v * Wl[k * HID + ch];
    }
    hb[node * HID + ch] = f2bf(acc);
}

// ---------------- split-CSR gather (bf16 h, fp32 accumulate) ----------------
// 4 passes over src-quartile sub-bins; pass q touches only h rows in quartile q
__global__ void gather_bf16(const u32* __restrict__ h2, const int* __restrict__ rowptr,
                            const int2* __restrict__ esort, const float* __restrict__ dinv,
                            const float* __restrict__ b, float* __restrict__ agg,
                            int n, int do_relu) {
    int ch = threadIdx.x & 31;
    int node = blockIdx.x * 8 + (threadIdx.x >> 5);
    if (node >= n) return;
    int p = ch >> 1, hi = ch & 1;
    float dv = dinv[node];
    float acc = dv * dv * bfx(h2[node * 16 + p], hi) + b[ch];
#pragma unroll
    for (int q = 0; q < NSPLIT; ++q) {
        int g0 = q * n + node;
        int start = rowptr[g0], end = rowptr[g0 + 1];
        int j = start;
        for (; j + 4 <= end; j += 4) {
            int2 e0 = esort[j];
            int2 e1 = esort[j + 1];
            int2 e2 = esort[j + 2];
            int2 e3 = esort[j + 3];
            u32 v0 = h2[e0.x * 16 + p];
            u32 v1 = h2[e1.x * 16 + p];
            u32 v2 = h2[e2.x * 16 + p];
            u32 v3 = h2[e3.x * 16 + p];
            acc += __int_as_float(e0.y) * bfx(v0, hi);
            acc += __int_as_float(e1.y) * bfx(v1, hi);
            acc += __int_as_float(e2.y) * bfx(v2, hi);
            acc += __int_as_float(e3.y) * bfx(v3, hi);
        }
        for (; j < end; ++j) {
            int2 ed = esort[j];
            acc += __int_as_float(ed.y) * bfx(h2[ed.x * 16 + p], hi);
        }
    }
    if (do_relu) acc = fmaxf(acc, 0.f);
    agg[node * HID + ch] = acc;
}

// ---------------- BN stats reduce ----------------
__global__ void bn_reduce(const float* __restrict__ agg, float* __restrict__ stats, int n) {
    __shared__ float s1[256], s2[256];
    int ch = threadIdx.x & 31, rg = threadIdx.x >> 5;
    float a = 0.f, b = 0.f;
    for (int node = blockIdx.x * 8 + rg; node < n; node += gridDim.x * 8) {
        float v = agg[node * HID + ch];
        a += v;
        b += v * v;
    }
    s1[threadIdx.x] = a;
    s2[threadIdx.x] = b;
    __syncthreads();
    if (threadIdx.x < 32) {
        float ta = 0.f, tb = 0.f;
#pragma unroll
        for (int j = 0; j < 8; ++j) {
            ta += s1[j * 32 + threadIdx.x];
            tb += s2[j * 32 + threadIdx.x];
        }
        atomicAdd(&stats[threadIdx.x], ta);
        atomicAdd(&stats[32 + threadIdx.x], tb);
    }
}

extern "C" void kernel_launch(void* const* d_in, const int* in_sizes, int n_in,
                              void* d_out, int out_size, void* d_ws, size_t ws_size,
                              hipStream_t stream) {
    const int N = in_sizes[0] / DIN;
    const int E = in_sizes[2];
    const int N4 = NSPLIT * N;
    const u32 qdiv = (u32)((N + NSPLIT - 1) / NSPLIT);

    const float* x = (const float*)d_in[0];
    const int* ei = (const int*)d_in[1];
    const float* ew = (const float*)d_in[2];
    const int* row = ei;
    const int* col = ei + E;

    const float* Ws[4] = {(const float*)d_in[3], (const float*)d_in[5],
                          (const float*)d_in[7], (const float*)d_in[9]};
    const float* bs[4] = {(const float*)d_in[4], (const float*)d_in[6],
                          (const float*)d_in[8], (const float*)d_in[10]};
    const float* gs[3] = {(const float*)d_in[11], (const float*)d_in[13], (const float*)d_in[15]};
    const float* bes[3] = {(const float*)d_in[12], (const float*)d_in[14], (const float*)d_in[16]};

    // workspace layout (~50 MB)
    char* wsb = (char*)d_ws;
    u64* cnt64 = (u64*)wsb;                          // 4N u64
    float* dinv = (float*)(cnt64 + N4);              // N f32
    int* rowptr = (int*)(dinv + N);                  // 4N+1 int
    int2* esort = (int2*)(rowptr + N4 + 1);          // E int2 (src, norm)
    u16* hbf = (u16*)(esort + E);                    // N*HID bf16 (gemm out)
    float* bufX = (float*)(hbf + (size_t)N * HID);   // N*HID f32 (raw agg; BN fused downstream)
    float* stats = bufX + (size_t)N * HID;           // 192 (3 layers x 64)
    int* bsum1 = (int*)(stats + 192);                // 2048
    int* bsum2 = bsum1 + 2048;                       // 512
    int* rank = (int*)bufX;  // E ints aliased: rank dead before bufX first written

    const int B = 256;
    const int ngrid = (N + B - 1) / B;
    const int n4grid = (N4 + B - 1) / B;
    const int egrid = (E + B - 1) / B;
    const int nodeGrid = (N + 7) / 8;
    const int B1 = (N4 + 255) / 256;          // level-1 scan blocks (1563 for N=100K)
    const int B2 = (B1 + 255) / 256;          // level-2 (7)
    const float invN = 1.0f / (float)N;

    // ---- build split CSR + norm ----
    init_cnt<<<n4grid, B, 0, stream>>>(cnt64, stats, N4);
    hist_rank<<<egrid, B, 0, stream>>>(row, col, ew, cnt64, rank, E, N, qdiv);
    finalize_deg<<<ngrid, B, 0, stream>>>(cnt64, rowptr, dinv, N);
    scan_blocks<<<B1, 256, 0, stream>>>(rowptr, bsum1, N4);
    scan_blocks<<<B2, 256, 0, stream>>>(bsum1, bsum2, B1);
    scan_tops<<<1, 512, 0, stream>>>(bsum2, B2);
    scan_addback<<<B2, 256, 0, stream>>>(bsum1, bsum2, B1, 0);      // sentinel into slack
    scan_addback<<<B1, 256, 0, stream>>>(rowptr, bsum1, N4, E);     // rowptr[4N] = E
    scatter_pos<<<egrid, B, 0, stream>>>(row, col, ew, dinv, rowptr, rank, esort, E, N, qdiv);

    // ---- layers ----
    for (int l = 0; l < 4; ++l) {
        if (l == 0)
            gemm_din<<<nodeGrid, B, 0, stream>>>(x, Ws[0], hbf, N);
        else
            gemm_hid_bn<<<nodeGrid, B, 0, stream>>>(bufX, Ws[l], stats + 64 * (l - 1),
                                                    gs[l - 1], bes[l - 1], hbf, N, invN);

        if (l < 3) {
            gather_bf16<<<nodeGrid, B, 0, stream>>>((const u32*)hbf, rowptr, esort, dinv,
                                                    bs[l], bufX, N, 0);
            bn_reduce<<<512, B, 0, stream>>>(bufX, stats + 64 * l, N);
        } else {
            gather_bf16<<<nodeGrid, B, 0, stream>>>((const u32*)hbf, rowptr, esort, dinv,
                                                    bs[l], (float*)d_out, N, 1);
        }
    }
}